// Round 2
// baseline (370.087 us; speedup 1.0000x reference)
//
#include <hip/hip_runtime.h>
#include <math.h>

// Problem constants (from reference)
#define B_      8
#define S_      4096
#define H_      2048
#define HINT_   4
#define WS_     16
#define STRIDE_ 8
#define MLPH_   64
#define NW_     512            // windows per batch
#define WPB_    8              // windows per block
#define ROWS_   72             // rows spanned per block: 8*WPB_ + 8
#define KT_     68             // k-tiles of 32 covering K=2052 padded to 2176
#define KPAD_   2176
#define NT_     4              // n-tiles of 16 covering MLPH_=64
#define PLD2_   65             // partLds row stride (floats); 65 mod 32 = 1 -> 2-way max

typedef float  floatx4 __attribute__((ext_vector_type(4)));
typedef short  shortx8 __attribute__((ext_vector_type(8)));

// d_ws layout (poison fill is unconditional -- proven R1 -- so d_ws is free):
//   [0, 17,825,792)        pooled bf16 [4096 rows][2176 cols]
//   [18,874,368, +278,528) W1B packed bf16 MFMA B-fragments
#define W1B_BYTE_OFF 18874368

__device__ __forceinline__ unsigned short f2b(float x) {
    // float -> bf16, round-to-nearest-even (inputs are finite normals)
    unsigned u = __float_as_uint(x);
    u += 0x7FFFu + ((u >> 16) & 1u);
    return (unsigned short)(u >> 16);
}

// Repack W1 (2052 x 64, row-major fp32) into bf16 MFMA B-fragment order:
// nt, kt, lane L, j:  B[k = kt*32 + (L>>4)*8 + j][n = nt*16 + (L&15)]
// flat: (((nt*KT_ + kt)*64 + L)*8 + j). Zero-pad k >= 2052.
__global__ void prep_w1(const float* __restrict__ W1, unsigned short* __restrict__ W1B) {
    const int blk  = blockIdx.x;            // 0 .. NT_*KT_-1
    const int nt   = blk / KT_;
    const int kt   = blk % KT_;
    const int lane = threadIdx.x;           // 64 threads
    const int n     = nt * 16 + (lane & 15);
    const int kbase = kt * 32 + (lane >> 4) * 8;
    unsigned short tmp[8];
#pragma unroll
    for (int j = 0; j < 8; ++j) {
        const int k = kbase + j;
        const float v = (k < (H_ + HINT_)) ? W1[(size_t)k * MLPH_ + n] : 0.0f;
        tmp[j] = f2b(v);
    }
    *(uint4*)(W1B + (((size_t)nt * KT_ + kt) * 64 + lane) * 8) = *(const uint4*)tmp;
}

// ---------------------------------------------------------------------------
// pool_kernel: pure streaming. 512 blocks x 512 threads, 8 windows/block.
// No MFMA state, ~0.3 KB LDS -> isolated register budget, every wave busy
// from first load to last store. Writes pooled bf16 rows (k-padded) to d_ws.
// ---------------------------------------------------------------------------
__global__ __launch_bounds__(512, 6) void pool_kernel(
    const float* __restrict__ hidden,   // (B,S,H) fp32
    const int*   __restrict__ amask,    // (B,S) int32
    const float* __restrict__ hintf,    // (B,S,HINT) fp32
    unsigned short* __restrict__ pooled,// [4096][KPAD_] bf16
    float* __restrict__ out)            // [4096:8192) window_mask
{
    __shared__ float amLds[ROWS_];
    __shared__ float rinvLds[WPB_];

    const int tid = threadIdx.x;
    const int bid = blockIdx.x;                    // 512 blocks
    // XCD-locality swizzle: consecutive chunks land on the same XCD (halo L2 reuse)
    const int gid   = (bid & 7) * 64 + (bid >> 3);
    const int b     = gid >> 6;
    const int chunk = gid & 63;
    const int w0    = chunk * WPB_;
    const int s0    = chunk * (WPB_ * STRIDE_);
    const int gw0   = b * NW_ + w0;                // global pooled row base

    // stage mask (am==0 for p>=S_ also guards the OOB row addresses below)
    if (tid < ROWS_) {
        const int p = s0 + tid;
        amLds[tid] = (p < S_) ? (float)amask[b * S_ + p] : 0.0f;
    }
    // zero k-pad cols 2052..2175 of this block's 8 pooled rows (62 uints x 8)
    if (tid < 8 * 62) {
        const int row = tid / 62, cc = tid % 62;
        *(unsigned*)&pooled[(size_t)(gw0 + row) * KPAD_ + 2052 + cc * 2] = 0u;
    }
    __syncthreads();

    // denoms + window_mask output
    if (tid < WPB_) {
        float s = 0.f;
#pragma unroll
        for (int k = 0; k < WS_; ++k) s += amLds[tid * STRIDE_ + k];
        rinvLds[tid] = 1.0f / fmaxf(s, 1.0f);
        out[(size_t)(B_ * NW_) + (size_t)b * NW_ + w0 + tid] = (s > 0.f) ? 1.0f : 0.0f;
    }
    __syncthreads();

    // BRANCH-FREE masked pooling, rolling 2-group window. am is exactly 0/1:
    // select a 32-bit element offset (masked row vs dummy row s0, L1/L2-hot)
    // -> uniform SGPR base + VGPR offset, 8 independent 16-B loads in flight.
    const int c0 = tid * 4;
    const float* __restrict__ base = hidden + (size_t)b * S_ * H_;
    const unsigned rowOff0 = (unsigned)(s0 * H_ + c0);

    floatx4 prev = (floatx4){0.f, 0.f, 0.f, 0.f};
#pragma unroll
    for (int g = 0; g <= WPB_; ++g) {
        float    am [STRIDE_];
        unsigned off[STRIDE_];
#pragma unroll
        for (int k = 0; k < STRIDE_; ++k) {
            const int rr = g * STRIDE_ + k;
            am[k]  = amLds[rr];
            off[k] = (am[k] != 0.0f) ? rowOff0 + (unsigned)(rr * H_) : rowOff0;
        }
        floatx4 v[STRIDE_];
#pragma unroll
        for (int k = 0; k < STRIDE_; ++k) v[k] = *(const floatx4*)(base + off[k]);

        floatx4 cur = (floatx4){0.f, 0.f, 0.f, 0.f};
#pragma unroll
        for (int k = 0; k < STRIDE_; ++k) {
            cur.x = fmaf(am[k], v[k].x, cur.x);
            cur.y = fmaf(am[k], v[k].y, cur.y);
            cur.z = fmaf(am[k], v[k].z, cur.z);
            cur.w = fmaf(am[k], v[k].w, cur.w);
        }
        if (g >= 1) {                              // finalize window w = g-1
            const int w = g - 1;
            const floatx4 s = prev + cur;
            const float r = rinvLds[w];
            unsigned short q[4];
            q[0] = f2b(s.x * r); q[1] = f2b(s.y * r);
            q[2] = f2b(s.z * r); q[3] = f2b(s.w * r);
            *(uint2*)(&pooled[(size_t)(gw0 + w) * KPAD_ + c0]) = *(const uint2*)q;
        }
        prev = cur;
    }

    if (tid < WPB_ * HINT_) {                      // hint pooling: 32 threads
        const int w = tid >> 2, hc = tid & 3;
        float s = 0.f;
#pragma unroll
        for (int k = 0; k < WS_; ++k) {
            const int rr = w * STRIDE_ + k;
            const float amv = amLds[rr];
            float hv = 0.f;
            if (amv != 0.0f)                       // tiny, 32 threads only
                hv = hintf[((size_t)b * S_ + (s0 + rr)) * HINT_ + hc];
            s += amv * hv;
        }
        pooled[(size_t)(gw0 + w) * KPAD_ + H_ + hc] = f2b(s * rinvLds[w]);
    }
}

// ---------------------------------------------------------------------------
// mlp_kernel: tiny GEMM (4096 x 2176) @ (2176 x 64) + gelu + W2 reduce.
// 128 blocks x 8 waves: wave = (mtile = wid&1 [16 rows], ntile = wid>>1).
// A-frags straight from pooled (L2/L3-hot, just written); B-frags from W1B.
// ---------------------------------------------------------------------------
__global__ __launch_bounds__(512, 2) void mlp_kernel(
    const unsigned short* __restrict__ pooled,
    const unsigned short* __restrict__ W1B,
    const float* __restrict__ b1,       // (64)
    const float* __restrict__ W2,       // (64)
    const float* __restrict__ b2,       // (1)
    float* __restrict__ out)            // [0:4096) logits
{
    __shared__ float partLds[32 * PLD2_];          // 32 rows x 64 cols, 8.3 KB

    const int tid  = threadIdx.x;
    const int wid  = tid >> 6;
    const int lane = tid & 63;
    const int blk  = blockIdx.x;                   // 128 blocks, 32 windows each
    const int mrow = (wid & 1) * 16;               // local row tile
    const int nt   = wid >> 1;                     // n-tile 0..3

    // A-frag: lane holds A[m = mrow + (lane&15)][k = kt*32 + (lane>>4)*8 + j]
    const unsigned short* aBase =
        pooled + (size_t)(blk * 32 + mrow + (lane & 15)) * KPAD_ + (lane >> 4) * 8;
    const unsigned short* bBase = W1B + ((size_t)nt * KT_ * 64 + lane) * 8;

    floatx4 dacc = (floatx4){0.f, 0.f, 0.f, 0.f};
#pragma unroll 4
    for (int kt = 0; kt < KT_; ++kt) {
        const shortx8 af = *(const shortx8*)(aBase + kt * 32);
        const shortx8 bf = *(const shortx8*)(bBase + (size_t)kt * 512);
        dacc = __builtin_amdgcn_mfma_f32_16x16x32_bf16(af, bf, dacc, 0, 0, 0);
    }
    // D: lane reg r holds D[row = (lane>>4)*4 + r][col = lane&15]
    {
        const int r0 = mrow + (lane >> 4) * 4;
        const int c  = nt * 16 + (lane & 15);
        partLds[(r0 + 0) * PLD2_ + c] = dacc[0];
        partLds[(r0 + 1) * PLD2_ + c] = dacc[1];
        partLds[(r0 + 2) * PLD2_ + c] = dacc[2];
        partLds[(r0 + 3) * PLD2_ + c] = dacc[3];
    }
    __syncthreads();

    // epilogue: wave wid handles rows wid*4 .. wid*4+3; lane = hidden unit j
    const float b1v = b1[lane];
    const float w2v = W2[lane];
#pragma unroll
    for (int rr = 0; rr < 4; ++rr) {
        const int row = wid * 4 + rr;
        const float a = partLds[row * PLD2_ + lane] + b1v;
        float g = 0.5f * a * (1.0f + erff(a * 0.70710678118654752f)) * w2v;
#pragma unroll
        for (int off = 32; off > 0; off >>= 1) g += __shfl_down(g, off, 64);
        if (lane == 0) out[(size_t)blk * 32 + row] = g + b2[0];
    }
}

extern "C" void kernel_launch(void* const* d_in, const int* in_sizes, int n_in,
                              void* d_out, int out_size, void* d_ws, size_t ws_size,
                              hipStream_t stream) {
    const float* hidden = (const float*)d_in[0];
    const int*   amask  = (const int*)d_in[1];
    const float* hintf  = (const float*)d_in[2];
    const float* W1     = (const float*)d_in[3];
    const float* b1     = (const float*)d_in[4];
    const float* W2     = (const float*)d_in[5];
    const float* b2     = (const float*)d_in[6];
    float* out          = (float*)d_out;

    unsigned short* pooled = (unsigned short*)d_ws;
    unsigned short* W1B    = (unsigned short*)((char*)d_ws + W1B_BYTE_OFF);

    prep_w1<<<NT_ * KT_, 64, 0, stream>>>(W1, W1B);
    pool_kernel<<<B_ * (NW_ / WPB_), 512, 0, stream>>>(hidden, amask, hintf, pooled, out);
    mlp_kernel<<<(B_ * NW_) / 32, 512, 0, stream>>>(pooled, W1B, b1, W2, b2, out);
}

// Round 5
// 349.023 us; speedup vs baseline: 1.0604x; 1.0604x over previous
//
#include <hip/hip_runtime.h>
#include <math.h>

// Problem constants (from reference)
#define B_      8
#define S_      4096
#define H_      2048
#define HINT_   4
#define WS_     16
#define STRIDE_ 8
#define MLPH_   64
#define NW_     512            // windows per batch
#define WPB_    8              // windows per block
#define ROWS_   72             // rows spanned per block: 8*WPB_ + 8
#define KT_     68             // k-tiles of 32 covering K=2052 padded to 2176
#define KPAD_   2176
#define LDK_    2184           // LDS row stride in shorts (pad 8)
#define NT_     4              // n-tiles of 16 covering MLPH_=64
#define PLD_    66             // partLds row stride (floats)

typedef float  floatx4 __attribute__((ext_vector_type(4)));
typedef short  shortx8 __attribute__((ext_vector_type(8)));

__device__ __forceinline__ unsigned short f2b(float x) {
    // float -> bf16, round-to-nearest-even (inputs are finite normals)
    unsigned u = __float_as_uint(x);
    u += 0x7FFFu + ((u >> 16) & 1u);
    return (unsigned short)(u >> 16);
}

// ---------------------------------------------------------------------------
// prep_w1, coalesced: 68 blocks (one kt each) x 256 threads.
// Load the 32x64 fp32 sub-tile of W1 with contiguous float4s (32 B/thread),
// transpose through LDS, emit bf16 MFMA B-fragments:
//   W1B[(((nt*KT_+kt)*64+L)*8+j] = bf16(W1[k*64+n]), k=kt*32+(L>>4)*8+j,
//   n=nt*16+(L&15); zero for k >= 2052.
// ---------------------------------------------------------------------------
__global__ void prep_w1(const float* __restrict__ W1, unsigned short* __restrict__ W1B) {
    __shared__ float tile[32][65];                 // +1 pad: <=2-way banks (free)
    const int kt = blockIdx.x;
    const int t  = threadIdx.x;

    const int kl = t >> 3;                         // 0..31 local k row
    const int n0 = (t & 7) * 8;                    // 0,8,..,56
    const int kg = kt * 32 + kl;
    floatx4 a = (floatx4){0.f,0.f,0.f,0.f}, c = a;
    if (kg < (H_ + HINT_)) {
        a = *(const floatx4*)&W1[(size_t)kg * MLPH_ + n0];
        c = *(const floatx4*)&W1[(size_t)kg * MLPH_ + n0 + 4];
    }
    tile[kl][n0+0]=a.x; tile[kl][n0+1]=a.y; tile[kl][n0+2]=a.z; tile[kl][n0+3]=a.w;
    tile[kl][n0+4]=c.x; tile[kl][n0+5]=c.y; tile[kl][n0+6]=c.z; tile[kl][n0+7]=c.w;
    __syncthreads();

    const int nt = t >> 6, L = t & 63;
    const int n  = nt * 16 + (L & 15);
    const int kb = (L >> 4) * 8;
    unsigned short q[8];
#pragma unroll
    for (int j = 0; j < 8; ++j) q[j] = f2b(tile[kb + j][n]);
    *(uint4*)(W1B + (((size_t)nt * KT_ + kt) * 64 + L) * 8) = *(const uint4*)q;
}

__global__ __launch_bounds__(512, 6) void wbh_kernel(
    const float* __restrict__ hidden,   // (B,S,H) fp32
    const int*   __restrict__ amask,    // (B,S) int32
    const float* __restrict__ hintf,    // (B,S,HINT) fp32
    const float* __restrict__ b1,       // (64)
    const float* __restrict__ W2,       // (64)
    const float* __restrict__ b2,       // (1)
    const unsigned short* __restrict__ W1B, // packed bf16 W1 fragments
    float* __restrict__ out)            // [0:4096) logits, [4096:8192) mask
{
    // 8 real window rows only; MFMA lanes with m>=8 alias row m&7 (dup D rows
    // are never read). LDS total ~37.4 KB.
    __shared__ unsigned short pooledLds[WPB_ * LDK_];   // 34,944 B
    __shared__ float amLds[ROWS_];
    __shared__ float rinvLds[WPB_];
    __shared__ float partLds[WPB_ * PLD_];

    const int tid = threadIdx.x;
    const int bid = blockIdx.x;                    // 512 blocks
    // XCD-locality swizzle: consecutive chunks land on the same XCD (halo L2 reuse)
    const int gid   = (bid & 7) * 64 + (bid >> 3);
    const int b     = gid >> 6;
    const int chunk = gid & 63;
    const int w0    = chunk * WPB_;
    const int s0    = chunk * (WPB_ * STRIDE_);

    // ---- Phase 0: zero k-pad cols (2052..2175) of the 8 rows; stage mask ----
    if (tid < 8 * 62) {                            // 62 uints x 8 rows
        const int row = tid / 62, cc = tid % 62;
        *(unsigned*)&pooledLds[row * LDK_ + 2052 + cc * 2] = 0u;
    }
    if (tid < ROWS_) {
        const int p = s0 + tid;
        amLds[tid] = (p < S_) ? (float)amask[b * S_ + p] : 0.0f;
    }
    __syncthreads();

    // ---- Phase 1a: denoms + window_mask output ----
    if (tid < WPB_) {
        float s = 0.f;
#pragma unroll
        for (int k = 0; k < WS_; ++k) s += amLds[tid * STRIDE_ + k];
        rinvLds[tid] = 1.0f / fmaxf(s, 1.0f);
        out[(size_t)(B_ * NW_) + (size_t)b * NW_ + w0 + tid] = (s > 0.f) ? 1.0f : 0.0f;
    }
    __syncthreads();

    // ---- Phase 1b: BRANCH-FREE masked pooling, rolling 2-group window ----
    // Weight am is exactly 0.0/1.0: select address (masked row vs dummy row 0,
    // L1-resident) and FMA by am. All 8 loads of a group are unconditional and
    // independent -> issued back-to-back, fine-grained vmcnt drain, ~8 KB in
    // flight per wave instead of 1 KB (the round-2/3 serialization killer).
    const int c0 = tid * 4;
    const float* rowBase = hidden + ((size_t)b * S_ + s0) * H_ + c0;

    floatx4 prev = (floatx4){0.f, 0.f, 0.f, 0.f};
#pragma unroll
    for (int g = 0; g <= WPB_; ++g) {
        float am[STRIDE_];
        const float* ptr[STRIDE_];
#pragma unroll
        for (int k = 0; k < STRIDE_; ++k) {
            const int rr = g * STRIDE_ + k;
            am[k]  = amLds[rr];
            ptr[k] = (am[k] != 0.0f) ? (rowBase + (size_t)rr * H_) : rowBase;
        }
        floatx4 v[STRIDE_];
#pragma unroll
        for (int k = 0; k < STRIDE_; ++k) v[k] = *(const floatx4*)ptr[k];

        floatx4 cur = (floatx4){0.f, 0.f, 0.f, 0.f};
#pragma unroll
        for (int k = 0; k < STRIDE_; ++k) {
            cur.x = fmaf(am[k], v[k].x, cur.x);
            cur.y = fmaf(am[k], v[k].y, cur.y);
            cur.z = fmaf(am[k], v[k].z, cur.z);
            cur.w = fmaf(am[k], v[k].w, cur.w);
        }
        if (g >= 1) {                              // finalize window w = g-1
            const int w = g - 1;
            const floatx4 s = prev + cur;
            const float r = rinvLds[w];
            unsigned short q[4];
            q[0] = f2b(s.x * r); q[1] = f2b(s.y * r);
            q[2] = f2b(s.z * r); q[3] = f2b(s.w * r);
            *(uint2*)(&pooledLds[w * LDK_ + c0]) = *(const uint2*)q;
        }
        prev = cur;
    }

    if (tid < WPB_ * HINT_) {                      // hint pooling: 32 threads
        const int w = tid >> 2, hc = tid & 3;
        float s = 0.f;
#pragma unroll
        for (int k = 0; k < WS_; ++k) {
            const int rr = w * STRIDE_ + k;
            const float amv = amLds[rr];
            float hv = 0.f;
            if (amv != 0.0f)                       // tiny, 32 threads only
                hv = hintf[((size_t)b * S_ + (s0 + rr)) * HINT_ + hc];
            s += amv * hv;
        }
        pooledLds[w * LDK_ + H_ + hc] = f2b(s * rinvLds[w]);
    }
    __syncthreads();

    // ---- Phase 2: MFMA (16x2176)@(2176x64); waves 0..3 = n-tiles, full K ----
    // Two accumulators halve the serial MFMA dependency chain (68 -> 34).
    const int wid  = tid >> 6;
    const int lane = tid & 63;
    if (wid < NT_) {
        floatx4 d0 = (floatx4){0.f, 0.f, 0.f, 0.f};
        floatx4 d1 = (floatx4){0.f, 0.f, 0.f, 0.f};
        // A-frag: lane holds A[m=lane&15][k=kt*32+(lane>>4)*8+j]; row aliased m&7
        const unsigned short* aBase = pooledLds + (lane & 7) * LDK_ + (lane >> 4) * 8;
        const unsigned short* bBase = W1B + ((size_t)wid * KT_ * 64 + lane) * 8;
#pragma unroll 4
        for (int kt = 0; kt < KT_; kt += 2) {
            const shortx8 a0  = *(const shortx8*)(aBase + kt * 32);
            const shortx8 b0  = *(const shortx8*)(bBase + (size_t)kt * 512);
            const shortx8 a1  = *(const shortx8*)(aBase + (kt + 1) * 32);
            const shortx8 b1f = *(const shortx8*)(bBase + (size_t)(kt + 1) * 512);
            d0 = __builtin_amdgcn_mfma_f32_16x16x32_bf16(a0, b0, d0, 0, 0, 0);
            d1 = __builtin_amdgcn_mfma_f32_16x16x32_bf16(a1, b1f, d1, 0, 0, 0);
        }
        const floatx4 dacc = d0 + d1;
        // D: lane reg r holds D[row=(lane>>4)*4+r][col=lane&15]; rows >=8 dups
        if (lane < 32) {
            const int m0 = (lane >> 4) * 4;
            const int j  = wid * 16 + (lane & 15);
#pragma unroll
            for (int r = 0; r < 4; ++r)
                partLds[(m0 + r) * PLD_ + j] = dacc[r];
        }
    }
    __syncthreads();

    // ---- Phase 3: wave m = window m; lane j; gelu + W2 + shuffle reduce ----
    {
        const int m = tid >> 6;
        const int j = tid & 63;
        const float a = partLds[m * PLD_ + j] + b1[j];
        float g = 0.5f * a * (1.0f + erff(a * 0.70710678118654752f)) * W2[j];
#pragma unroll
        for (int off = 32; off > 0; off >>= 1) g += __shfl_down(g, off, 64);
        if (j == 0) out[(size_t)b * NW_ + w0 + m] = g + b2[0];
    }
}

extern "C" void kernel_launch(void* const* d_in, const int* in_sizes, int n_in,
                              void* d_out, int out_size, void* d_ws, size_t ws_size,
                              hipStream_t stream) {
    const float* hidden = (const float*)d_in[0];
    const int*   amask  = (const int*)d_in[1];
    const float* hintf  = (const float*)d_in[2];
    const float* W1     = (const float*)d_in[3];
    const float* b1     = (const float*)d_in[4];
    const float* W2     = (const float*)d_in[5];
    const float* b2     = (const float*)d_in[6];
    float* out          = (float*)d_out;

    unsigned short* W1B = (unsigned short*)d_ws;   // NT_*KT_*64*8*2 = 278,528 B
    // (d_ws poison fill is unconditional -- proven R1 -- so using it is free)

    prep_w1<<<KT_, 256, 0, stream>>>(W1, W1B);
    wbh_kernel<<<B_ * (NW_ / WPB_), 512, 0, stream>>>(
        hidden, amask, hintf, b1, W2, b2, W1B, out);
}